// Round 5
// baseline (788.926 us; speedup 1.0000x reference)
//
#include <hip/hip_runtime.h>
#include <hip/hip_bf16.h>
#include <stdint.h>

typedef float  f32x4 __attribute__((ext_vector_type(4)));
typedef short  s16x8 __attribute__((ext_vector_type(8)));
typedef unsigned short u16;

#define E_DIM 2048
#define NHEAD 16
#define DHEAD 128
#define NB    4
#define SQL   512
#define STOT  4096
#define SKV   3584
#define KOFF  ((size_t)33554432)   // k_new offset in d_out (floats)
#define OOFF  ((size_t)67108864)   // out_i offset in d_out (floats)

static __device__ __forceinline__ u16 f2b(float f){
  union { float f; uint32_t u; } v; v.f = f;
  uint32_t u = v.u;
  uint32_t r = ((u >> 16) & 1u) + 0x7fffu;   // RNE
  return (u16)((u + r) >> 16);
}

static __device__ __forceinline__ float redmax16(float v){
  v = fmaxf(v, __shfl_xor(v, 1));
  v = fmaxf(v, __shfl_xor(v, 2));
  v = fmaxf(v, __shfl_xor(v, 4));
  v = fmaxf(v, __shfl_xor(v, 8));
  return v;
}
static __device__ __forceinline__ float redsum16(float v){
  v += __shfl_xor(v, 1);
  v += __shfl_xor(v, 2);
  v += __shfl_xor(v, 4);
  v += __shfl_xor(v, 8);
  return v;
}

#define GLD_LDS16(gp, lp) \
  __builtin_amdgcn_global_load_lds((const __attribute__((address_space(1))) void*)(gp), \
                                   (__attribute__((address_space(3))) void*)(lp), 16, 0, 0)

// V-tile swizzle: mixes d bits 0-2 with 3-5 so lanes writing strided d spread banks.
#define SWZV(d) ((((d) ^ ((d) >> 3)) & 7) << 4)

// ---------------- prep: fused W-transpose (blocks 0..4095) + x cast (4096..6143) ----------------
__global__ __launch_bounds__(256) void prep_kernel(
    const float* __restrict__ x, u16* __restrict__ xbf,
    const float* __restrict__ Wq, const float* __restrict__ Wk,
    const float* __restrict__ Wv, const float* __restrict__ Wo,
    u16* __restrict__ wt)
{
  __shared__ float tile[64][65];
  const int bid = blockIdx.x;
  const int t = threadIdx.x;
  if (bid >= 4096){
    size_t i = (size_t)(bid - 4096) * 256 + t;   // chunk of 8 floats
    f32x4 a = __builtin_nontemporal_load((const f32x4*)x + 2*i);
    f32x4 b = __builtin_nontemporal_load((const f32x4*)x + 2*i + 1);
    union { u16 us[8]; uint4 v; } r;
    r.us[0]=f2b(a[0]); r.us[1]=f2b(a[1]); r.us[2]=f2b(a[2]); r.us[3]=f2b(a[3]);
    r.us[4]=f2b(b[0]); r.us[5]=f2b(b[1]); r.us[6]=f2b(b[2]); r.us[7]=f2b(b[3]);
    ((uint4*)xbf)[i] = r.v;
    return;
  }
  const int z = bid >> 10, rem = bid & 1023;
  const float* src = (z==0)?Wq : (z==1)?Wk : (z==2)?Wv : Wo;
  u16* dst = wt + (size_t)z * E_DIM * E_DIM;
  const int r0 = (rem & 31)*64, c0 = (rem >> 5)*64;
  #pragma unroll 4
  for (int it=0; it<16; it++){
    int idx = it*256 + t; int r = idx>>6, c = idx&63;
    tile[r][c] = __builtin_nontemporal_load(src + (size_t)(r0+r)*E_DIM + c0 + c);
  }
  __syncthreads();
  #pragma unroll 4
  for (int it=0; it<16; it++){
    int idx = it*256 + t; int rr = idx>>6, cc = idx&63;
    dst[(size_t)(c0+rr)*E_DIM + r0 + cc] = f2b(tile[cc][rr]);
  }
}

// ---------------- fused QKV GEMM (blocks 0..767) + cache concat copy (768..15103) ----------------
// GEMM: m97 structure, 128x128 tiles, BK=32. Copy: 587 MB HBM stream, overlaps GEMM's MFMA.
// Disjoint writes: copy fills cache rows [0,SKV), GEMM epilogue fills [SKV,STOT).
__global__ __launch_bounds__(256) void qkvcopy_kernel(
    const u16* __restrict__ A, const u16* __restrict__ Wt,
    const float* __restrict__ b0, const float* __restrict__ b1, const float* __restrict__ b2,
    const float* __restrict__ vsrc, const float* __restrict__ ksrc,
    float* __restrict__ dout, u16* __restrict__ qbf,
    u16* __restrict__ kcb, u16* __restrict__ vcb, int usebf)
{
  __shared__ __align__(16) u16 As[128*32];
  __shared__ __align__(16) u16 Bs[128*32];
  const int bid = blockIdx.x;
  const int t = threadIdx.x;

  if (bid >= 768){
    // -------- copy part: 14336 blocks x 1024 float4 chunks --------
    int cid = bid - 768;
    int arr = (cid >= 7168);
    int c2 = arr ? cid - 7168 : cid;
    int b = c2 / 1792;
    int xb = c2 - b*1792;
    const f32x4* s4 = (const f32x4*)((arr ? ksrc : vsrc) + (size_t)b*7340032);
    f32x4* d4       = (f32x4*)(dout + (arr ? KOFF : 0) + (size_t)b*8388608);
    u16*   db       = (arr ? kcb : vcb) + (size_t)b*8388608;
    #pragma unroll
    for (int it=0; it<4; it++){
      int idx = xb*1024 + it*256 + t;
      f32x4 val = __builtin_nontemporal_load(s4 + idx);
      __builtin_nontemporal_store(val, d4 + idx);
      if (usebf){
        union { u16 us[4]; uint2 u; } p;
        p.us[0]=f2b(val[0]); p.us[1]=f2b(val[1]); p.us[2]=f2b(val[2]); p.us[3]=f2b(val[3]);
        *(uint2*)(db + (size_t)idx*4) = p.u;
      }
    }
    return;
  }

  // -------- GEMM part: MODE-0 body (Q/K/V projections) --------
  const int l = t & 63, w = t >> 6;
  const int lr = l & 15, lh = l >> 4;
  const int m0 = (bid & 15) * 128;
  const int y  = bid >> 4;
  const int mat = y >> 4;
  const int n0  = (y & 15) * 128;
  const u16* Bp = Wt + (size_t)mat * E_DIM * E_DIM;
  const float* bias = (mat==0 ? b0 : (mat==1 ? b1 : b2));
  const int wm = (w>>1)*64, wn = (w&1)*64;

  f32x4 acc[4][4] = {};

  for (int k0 = 0; k0 < E_DIM; k0 += 32){
    __syncthreads();
    #pragma unroll
    for (int it=0; it<2; it++){
      int c = it*256 + t;
      int row = c>>2, j = c&3, g = j ^ (row&3);   // 4-way XOR pre-swizzle
      GLD_LDS16(Bp + (size_t)(n0+row)*E_DIM + k0 + g*8, (char*)Bs + c*16);
      GLD_LDS16(A  + (size_t)(m0+row)*E_DIM + k0 + g*8, (char*)As + c*16);
    }
    __syncthreads();
    s16x8 af[4], bfr[4];
    #pragma unroll
    for (int m=0;m<4;m++){
      int row = wm + m*16 + lr;
      af[m] = *(const s16x8*)((const char*)As + row*64 + ((lh ^ (row&3))<<4));
    }
    #pragma unroll
    for (int n=0;n<4;n++){
      int nn = wn + n*16 + lr;
      bfr[n] = *(const s16x8*)((const char*)Bs + nn*64 + ((lh ^ (nn&3))<<4));
    }
    __builtin_amdgcn_s_setprio(1);
    #pragma unroll
    for (int m=0;m<4;m++)
      #pragma unroll
      for (int n=0;n<4;n++)
        acc[m][n] = __builtin_amdgcn_mfma_f32_16x16x32_bf16(af[m], bfr[n], acc[m][n], 0,0,0);
    __builtin_amdgcn_s_setprio(0);
  }

  // epilogue: C layout col = lane&15, row = (lane>>4)*4 + reg
  #pragma unroll
  for (int n=0;n<4;n++){
    int col = n0 + wn + n*16 + lr;
    float bc = bias[col];
    #pragma unroll
    for (int m=0;m<4;m++){
      int rbase = m0 + wm + m*16 + lh*4;
      #pragma unroll
      for (int j=0;j<4;j++){
        float val = acc[m][n][j] + bc;
        int row = rbase + j;
        if (mat == 0){
          qbf[(size_t)row*E_DIM + col] = f2b(val);
        } else {
          int b = row >> 9, sq = row & 511;
          size_t o = ((size_t)b*STOT + SKV + sq)*(size_t)E_DIM + col;
          float* ob = dout + (mat==1 ? KOFF : 0);
          __builtin_nontemporal_store(val, ob + o);
          if (usebf) (mat==1 ? kcb : vcb)[o] = f2b(val);
        }
      }
    }
  }
}

// ---------------- out-projection GEMM: 64x128 tiles (grid 32x16), m97 structure ----------------
__global__ __launch_bounds__(256) void gemm_out_kernel(
    const u16* __restrict__ A, const u16* __restrict__ Wt,
    const float* __restrict__ bias, float* __restrict__ dout)
{
  __shared__ __align__(16) u16 As[64*32];
  __shared__ __align__(16) u16 Bs[128*32];
  const int t = threadIdx.x;
  const int l = t & 63, w = t >> 6;
  const int lr = l & 15, lh = l >> 4;
  const int m0 = blockIdx.x * 64;
  const int n0 = blockIdx.y * 128;
  const int wm = (w>>1)*32, wn = (w&1)*64;

  f32x4 acc[2][4] = {};

  for (int k0 = 0; k0 < E_DIM; k0 += 32){
    __syncthreads();
    #pragma unroll
    for (int it=0; it<2; it++){
      int c = it*256 + t;
      int row = c>>2, j = c&3, g = j ^ (row&3);   // 4-way XOR pre-swizzle
      GLD_LDS16(Wt + (size_t)(n0+row)*E_DIM + k0 + g*8, (char*)Bs + c*16);
      if (it==0)
        GLD_LDS16(A + (size_t)(m0+row)*E_DIM + k0 + g*8, (char*)As + c*16);
    }
    __syncthreads();
    s16x8 af[2], bfr[4];
    #pragma unroll
    for (int m=0;m<2;m++){
      int row = wm + m*16 + lr;
      af[m] = *(const s16x8*)((const char*)As + row*64 + ((lh ^ (row&3))<<4));
    }
    #pragma unroll
    for (int n=0;n<4;n++){
      int nn = wn + n*16 + lr;
      bfr[n] = *(const s16x8*)((const char*)Bs + nn*64 + ((lh ^ (nn&3))<<4));
    }
    __builtin_amdgcn_s_setprio(1);
    #pragma unroll
    for (int m=0;m<2;m++)
      #pragma unroll
      for (int n=0;n<4;n++)
        acc[m][n] = __builtin_amdgcn_mfma_f32_16x16x32_bf16(af[m], bfr[n], acc[m][n], 0,0,0);
    __builtin_amdgcn_s_setprio(0);
  }

  #pragma unroll
  for (int n=0;n<4;n++){
    int col = n0 + wn + n*16 + lr;
    float bc = bias[col];
    #pragma unroll
    for (int m=0;m<2;m++){
      int rbase = m0 + wm + m*16 + lh*4;
      #pragma unroll
      for (int j=0;j<4;j++){
        float val = acc[m][n][j] + bc;
        int row = rbase + j;
        __builtin_nontemporal_store(val, dout + OOFF + (size_t)row*E_DIM + col);
      }
    }
  }
}

// ---------------- flash attention: 256 blocks = (b, h, q-tile of 128), 8 waves x 16 q ----------------
// 2-phase pipeline: double-buffered Kt/Vt; issue t+1 staging loads before compute(t),
// write V(t+1) into LDS after PV(t); single barrier per tile.
template<int BF16KV>
__global__ __launch_bounds__(512) void attn_kernel(
    const u16* __restrict__ qbf,
    const u16* __restrict__ kcb, const u16* __restrict__ vcb,
    const float* __restrict__ kf32, const float* __restrict__ vf32,
    u16* __restrict__ valbf)
{
  __shared__ __align__(16) u16 Kt[2][64*128];   // [key][d], chunk-swizzled by key&7
  __shared__ __align__(16) u16 Vt[2][128*64];   // [d][key], SWZV-swizzled (transposed)
  __shared__ __align__(16) u16 Pl[8][16*64];    // per-wave P, XOR-swizzled by row&7
  const int t = threadIdx.x, l = t & 63, w = t >> 6;
  const int lr = l & 15, lh = l >> 4;
  // bijective XCD-chunked swizzle: blocks n with n%8==x cover orig ids [32x,32x+31]
  const int n = blockIdx.x;
  const int o = (n & 7)*32 + (n >> 3);
  const int b = o >> 6, h = (o >> 2) & 15, qt = o & 3;
  const int qrow0 = qt*128 + w*16;

  // staging geometry (fixed per thread)
  const int sv_k4 = (t >> 5) * 4;        // V: 4 consecutive keys
  const int sv_d0 = (t & 31) * 4;        // V: 4 consecutive d
  // staging registers (held across the compute phase)
  uint2 vreg[4];                         // BF16KV V path
  f32x4 vregf[4], kregf[4];              // f32 fallback paths

#define STAGE_ISSUE(S0N, NBUF) do {                                             \
    if (BF16KV){                                                                \
      _Pragma("unroll")                                                         \
      for (int it_=0; it_<2; it_++){                                            \
        int idx_ = it_*512 + t;                                                 \
        int key_ = idx_ >> 4, p_ = idx_ & 15, g_ = p_ ^ (key_ & 7);             \
        GLD_LDS16(kcb + ((size_t)b*STOT + (S0N) + key_)*E_DIM + h*DHEAD + g_*8, \
                  (char*)Kt[NBUF] + idx_*16);                                   \
      }                                                                         \
      _Pragma("unroll")                                                         \
      for (int i_=0; i_<4; i_++)                                                \
        vreg[i_] = *(const uint2*)(vcb + ((size_t)b*STOT + (S0N) + sv_k4 + i_)*E_DIM + h*DHEAD + sv_d0); \
    } else {                                                                    \
      _Pragma("unroll")                                                         \
      for (int it_=0; it_<2; it_++){                                            \
        int idx_ = it_*512 + t;                                                 \
        int key_ = idx_ >> 4, d0_ = (idx_ & 15)*8;                              \
        size_t src_ = ((size_t)b*STOT + (S0N) + key_)*E_DIM + h*DHEAD + d0_;    \
        kregf[2*it_]   = *(const f32x4*)(kf32 + src_);                          \
        kregf[2*it_+1] = *(const f32x4*)(kf32 + src_ + 4);                      \
      }                                                                         \
      _Pragma("unroll")                                                         \
      for (int i_=0; i_<4; i_++)                                                \
        vregf[i_] = *(const f32x4*)(vf32 + ((size_t)b*STOT + (S0N) + sv_k4 + i_)*E_DIM + h*DHEAD + sv_d0); \
    }                                                                           \
  } while(0)

#define STAGE_WRITE(NBUF) do {                                                  \
    u16 vv_[4][4];                                                              \
    if (BF16KV){                                                                \
      _Pragma("unroll")                                                         \
      for (int i_=0; i_<4; i_++){                                               \
        union { u16 us[4]; uint2 u; } r_; r_.u = vreg[i_];                      \
        vv_[i_][0]=r_.us[0]; vv_[i_][1]=r_.us[1]; vv_[i_][2]=r_.us[2]; vv_[i_][3]=r_.us[3]; \
      }                                                                         \
    } else {                                                                    \
      _Pragma("unroll")                                                         \
      for (int it_=0; it_<2; it_++){                                            \
        int idx_ = it_*512 + t;                                                 \
        int key_ = idx_ >> 4, d0_ = (idx_ & 15)*8;                              \
        union { u16 us[8]; s16x8 v; } p_;                                       \
        f32x4 f0_ = kregf[2*it_], f1_ = kregf[2*it_+1];                         \
        p_.us[0]=f2b(f0_[0]); p_.us[1]=f2b(f0_[1]); p_.us[2]=f2b(f0_[2]); p_.us[3]=f2b(f0_[3]); \
        p_.us[4]=f2b(f1_[0]); p_.us[5]=f2b(f1_[1]); p_.us[6]=f2b(f1_[2]); p_.us[7]=f2b(f1_[3]); \
        *(s16x8*)((char*)Kt[NBUF] + key_*256 + ((d0_*2) ^ ((key_&7)<<4))) = p_.v; \
      }                                                                         \
      _Pragma("unroll")                                                         \
      for (int i_=0; i_<4; i_++){                                               \
        vv_[i_][0]=f2b(vregf[i_][0]); vv_[i_][1]=f2b(vregf[i_][1]);             \
        vv_[i_][2]=f2b(vregf[i_][2]); vv_[i_][3]=f2b(vregf[i_][3]);             \
      }                                                                         \
    }                                                                           \
    _Pragma("unroll")                                                           \
    for (int dj_=0; dj_<4; dj_++){                                              \
      union { u16 us[4]; uint2 u; } p_;                                         \
      p_.us[0]=vv_[0][dj_]; p_.us[1]=vv_[1][dj_]; p_.us[2]=vv_[2][dj_]; p_.us[3]=vv_[3][dj_]; \
      int d_ = sv_d0 + dj_;                                                     \
      *(uint2*)((char*)Vt[NBUF] + d_*128 + ((sv_k4*2) ^ SWZV(d_))) = p_.u;      \
    }                                                                           \
  } while(0)

  // Q fragments held in registers for the whole kernel
  s16x8 qf[4];
  #pragma unroll
  for (int kc=0; kc<4; kc++){
    int R = b*SQL + qrow0 + lr;
    int col = h*DHEAD + kc*32 + lh*8;
    qf[kc] = *(const s16x8*)(qbf + (size_t)R*E_DIM + col);
  }

  f32x4 accO[8] = {};
  float m_run[4], l_run[4];
  #pragma unroll
  for (int j=0; j<4; j++){ m_run[j] = -1e30f; l_run[j] = 0.f; }

  const float C = 0.08838834764831845f * 1.44269504088896f;  // 1/sqrt(128) * log2(e)

  // prologue: stage tile 0 into buffer 0
  STAGE_ISSUE(0, 0);
  STAGE_WRITE(0);
  __syncthreads();

  int cur = 0;
  for (int tt=0; tt<64; tt++){
    const int s0 = tt*64;
    const int nxt = cur ^ 1;
    if (tt < 63) STAGE_ISSUE(s0 + 64, nxt);

    // ---- QK^T: S[64 keys] per wave (16 q-rows) ----
    f32x4 sv[4] = {};
    __builtin_amdgcn_s_setprio(1);
    #pragma unroll
    for (int kf=0; kf<4; kf++){
      int key = kf*16 + lr;
      #pragma unroll
      for (int kc=0; kc<4; kc++){
        s16x8 kb = *(const s16x8*)((char*)Kt[cur] + key*256 + ((kc*64 + lh*16) ^ ((key&7)<<4)));
        sv[kf] = __builtin_amdgcn_mfma_f32_16x16x32_bf16(qf[kc], kb, sv[kf], 0,0,0);
      }
    }
    __builtin_amdgcn_s_setprio(0);

    // ---- online softmax with defer-max (T13): skip alpha/rescale when max growth <= 8/C ----
    float vmj[4];
    float need = -1e30f;
    #pragma unroll
    for (int j=0; j<4; j++){
      float vm = fmaxf(fmaxf(sv[0][j], sv[1][j]), fmaxf(sv[2][j], sv[3][j]));
      vm = redmax16(vm);
      vmj[j] = vm;
      need = fmaxf(need, vm - m_run[j]);
    }
    const int skip = __all(need * C <= 8.0f);
    float alpha[4];
    #pragma unroll
    for (int j=0; j<4; j++){
      float mn = skip ? m_run[j] : fmaxf(m_run[j], vmj[j]);
      float a  = skip ? 1.0f : exp2f((m_run[j] - mn) * C);
      float rs = 0.f;
      #pragma unroll
      for (int kf=0; kf<4; kf++){
        float p = exp2f((sv[kf][j] - mn) * C);
        sv[kf][j] = p;
        rs += p;
      }
      rs = redsum16(rs);
      l_run[j] = l_run[j]*a + rs;
      m_run[j] = mn;
      alpha[j] = a;
    }
    if (!skip){
      #pragma unroll
      for (int nf=0; nf<8; nf++)
        #pragma unroll
        for (int j=0; j<4; j++)
          accO[nf][j] *= alpha[j];
    }
    // write P (bf16) to per-wave LDS, swizzled by row&7
    #pragma unroll
    for (int kf=0; kf<4; kf++)
      #pragma unroll
      for (int j=0; j<4; j++){
        int row = lh*4 + j;
        int col = kf*16 + lr;
        *(u16*)((char*)Pl[w] + row*128 + ((col*2) ^ ((row&7)<<4))) = f2b(sv[kf][j]);
      }
    asm volatile("s_waitcnt lgkmcnt(0)" ::: "memory");
    __builtin_amdgcn_sched_barrier(0);

    // ---- PV: O += P @ V ----
    #pragma unroll
    for (int kt=0; kt<2; kt++){
      s16x8 pa = *(const s16x8*)((char*)Pl[w] + lr*128 + ((kt*64 + lh*16) ^ ((lr&7)<<4)));
      __builtin_amdgcn_s_setprio(1);
      #pragma unroll
      for (int nf=0; nf<8; nf++){
        int d = nf*16 + lr;
        s16x8 vb = *(const s16x8*)((char*)Vt[cur] + d*128 + ((kt*64 + lh*16) ^ SWZV(d)));
        accO[nf] = __builtin_amdgcn_mfma_f32_16x16x32_bf16(pa, vb, accO[nf], 0,0,0);
      }
      __builtin_amdgcn_s_setprio(0);
    }

    if (tt < 63) STAGE_WRITE(nxt);
    __syncthreads();   // drains vmcnt (K gld_lds) + lgkm (V ds_writes) for next tile
    cur = nxt;
  }

  // ---- normalize + write values (bf16) for the output projection ----
  #pragma unroll
  for (int j=0; j<4; j++){
    float inv = 1.0f / l_run[j];
    int R = b*SQL + qrow0 + lh*4 + j;
    #pragma unroll
    for (int nf=0; nf<8; nf++){
      int col = h*DHEAD + nf*16 + lr;
      valbf[(size_t)R*E_DIM + col] = f2b(accO[nf][j] * inv);
    }
  }
#undef STAGE_ISSUE
#undef STAGE_WRITE
}

extern "C" void kernel_launch(void* const* d_in, const int* in_sizes, int n_in,
                              void* d_out, int out_size, void* d_ws, size_t ws_size,
                              hipStream_t stream){
  const float* x  = (const float*)d_in[0];
  const float* vc = (const float*)d_in[1];
  const float* kc = (const float*)d_in[2];
  const float* Wv = (const float*)d_in[3];
  const float* bv = (const float*)d_in[4];
  const float* Wq = (const float*)d_in[5];
  const float* bq = (const float*)d_in[6];
  const float* Wk = (const float*)d_in[7];
  const float* bk = (const float*)d_in[8];
  const float* Wo = (const float*)d_in[9];
  const float* bo = (const float*)d_in[10];
  float* out = (float*)d_out;
  char*  ws  = (char*)d_ws;

  u16* xbf  = (u16*)(ws);                           // 8 MB
  u16* wt   = (u16*)(ws + ((size_t)8  << 20));      // 32 MB (Wq^T,Wk^T,Wv^T,Wo^T)
  u16* qbf  = (u16*)(ws + ((size_t)40 << 20));      // 8 MB
  u16* valb = (u16*)(ws + ((size_t)48 << 20));      // 8 MB
  u16* kcb  = (u16*)(ws + ((size_t)56 << 20));      // 64 MB bf16 k cache
  u16* vcb  = (u16*)(ws + ((size_t)120 << 20));     // 64 MB bf16 v cache
  int usebf = (ws_size >= ((size_t)184 << 20)) ? 1 : 0;

  prep_kernel<<<6144, 256, 0, stream>>>(x, xbf, Wq, Wk, Wv, Wo, wt);
  qkvcopy_kernel<<<15104, 256, 0, stream>>>(xbf, wt, bq, bk, bv, vc, kc,
                                            out, qbf, kcb, vcb, usebf);
  if (usebf)
    attn_kernel<1><<<256, 512, 0, stream>>>(qbf, kcb, vcb, out + KOFF, out, valb);
  else
    attn_kernel<0><<<256, 512, 0, stream>>>(qbf, kcb, vcb, out + KOFF, out, valb);
  gemm_out_kernel<<<dim3(32,16), 256, 0, stream>>>(valb, wt + (size_t)3*E_DIM*E_DIM, bo, out);
}